// Round 1
// baseline (313.015 us; speedup 1.0000x reference)
//
#include <hip/hip_runtime.h>

#define Bn 4
#define Qn 1024
#define Kn 1024
#define Dd 256
#define Hh 64
#define Dv 256
#define TQ 8

// tanh(x) = 1 - 2/(exp(2x)+1); handles +/-inf saturation correctly.
__device__ __forceinline__ float fast_tanh(float x) {
    float e = __expf(2.f * x);
    return 1.f - __fdividef(2.f, e + 1.f);
}

// One block = 256 threads = 4 rows x 64 h-outputs. row dot(256) per thread.
// transpose=0: out[row*H + h]   (q projection, row-major)
// transpose=1: out[(b*H + h)*K + k]  (k projection, h-major for coalesced score loads)
__global__ __launch_bounds__(256) void proj_kernel(const float* __restrict__ X,
                                                   const float* __restrict__ W,
                                                   float* __restrict__ out,
                                                   int transpose) {
    int row = blockIdx.x * 4 + (threadIdx.x >> 6);
    int h = threadIdx.x & 63;
    const float4* x4 = (const float4*)(X + row * Dd);
    float acc = 0.f;
    #pragma unroll 4
    for (int d4 = 0; d4 < Dd / 4; ++d4) {
        float4 xv = x4[d4];
        int d = d4 * 4;
        acc = fmaf(xv.x, W[(d + 0) * Hh + h], acc);
        acc = fmaf(xv.y, W[(d + 1) * Hh + h], acc);
        acc = fmaf(xv.z, W[(d + 2) * Hh + h], acc);
        acc = fmaf(xv.w, W[(d + 3) * Hh + h], acc);
    }
    if (!transpose) {
        out[row * Hh + h] = acc;
    } else {
        int b = row >> 10;          // K = 1024
        int k = row & 1023;
        out[(b * Hh + h) * Kn + k] = acc;
    }
}

// One block handles TQ=8 query rows of one batch: scores -> softmax -> attn@V.
__global__ __launch_bounds__(256) void attn_kernel(const float* __restrict__ qp,
                                                   const float* __restrict__ kpt,
                                                   const float* __restrict__ V,
                                                   const float* __restrict__ wv,
                                                   float* __restrict__ out) {
    __shared__ __align__(16) float sc[TQ * Kn];        // 32 KB score tile
    __shared__ float4 qp4[TQ * (Hh / 4)];              // 2 KB q-proj tile
    __shared__ __align__(16) float wv_s[Hh];
    __shared__ float rinv_s[TQ];

    int tid = threadIdx.x;
    int b = blockIdx.x >> 7;               // 128 q-tiles per batch
    int qbase = (blockIdx.x & 127) * TQ;

    // stage q-proj tile + w_v into LDS
    const float* qrow = qp + (b * Qn + qbase) * Hh;
    for (int i = tid; i < TQ * Hh; i += 256) ((float*)qp4)[i] = qrow[i];
    if (tid < Hh) wv_s[tid] = wv[tid];
    __syncthreads();

    // ---- score phase: thread owns k = tid + 256*j ----
    const float* kb = kpt + b * Hh * Kn;
    for (int j = 0; j < Kn / 256; ++j) {
        int k = tid + j * 256;
        float s[TQ];
        #pragma unroll
        for (int q = 0; q < TQ; ++q) s[q] = 0.f;
        for (int h4 = 0; h4 < Hh / 4; ++h4) {
            int h = h4 * 4;
            float k0 = kb[(h + 0) * Kn + k];
            float k1 = kb[(h + 1) * Kn + k];
            float k2 = kb[(h + 2) * Kn + k];
            float k3 = kb[(h + 3) * Kn + k];
            float4 w4 = ((const float4*)wv_s)[h4];
            #pragma unroll
            for (int q = 0; q < TQ; ++q) {
                float4 qv = qp4[q * (Hh / 4) + h4];
                s[q] = fmaf(w4.x, fast_tanh(qv.x + k0), s[q]);
                s[q] = fmaf(w4.y, fast_tanh(qv.y + k1), s[q]);
                s[q] = fmaf(w4.z, fast_tanh(qv.z + k2), s[q]);
                s[q] = fmaf(w4.w, fast_tanh(qv.w + k3), s[q]);
            }
        }
        #pragma unroll
        for (int q = 0; q < TQ; ++q) sc[q * Kn + k] = s[q];
    }
    __syncthreads();

    // ---- softmax: wave w handles rows w and w+4 ----
    int wave = tid >> 6, lane = tid & 63;
    for (int rr = 0; rr < 2; ++rr) {
        int q = wave + rr * 4;
        float m = -1e30f;
        for (int i = lane; i < Kn; i += 64) m = fmaxf(m, sc[q * Kn + i]);
        #pragma unroll
        for (int off = 32; off >= 1; off >>= 1) m = fmaxf(m, __shfl_xor(m, off, 64));
        float sum = 0.f;
        for (int i = lane; i < Kn; i += 64) {
            float e = __expf(sc[q * Kn + i] - m);
            sc[q * Kn + i] = e;
            sum += e;
        }
        #pragma unroll
        for (int off = 32; off >= 1; off >>= 1) sum += __shfl_xor(sum, off, 64);
        if (lane == 0) rinv_s[q] = 1.f / sum;
    }
    __syncthreads();

    // ---- AV phase: thread owns column v = tid; V read once per block ----
    float acc[TQ];
    #pragma unroll
    for (int q = 0; q < TQ; ++q) acc[q] = 0.f;
    const float* Vb = V + b * Kn * Dv + tid;
    for (int k = 0; k < Kn; k += 4) {
        float v0 = Vb[(k + 0) * Dv];
        float v1 = Vb[(k + 1) * Dv];
        float v2 = Vb[(k + 2) * Dv];
        float v3 = Vb[(k + 3) * Dv];
        #pragma unroll
        for (int q = 0; q < TQ; ++q) {
            float4 p4 = *(const float4*)&sc[q * Kn + k];   // LDS b128 broadcast
            acc[q] = fmaf(p4.x, v0, acc[q]);
            acc[q] = fmaf(p4.y, v1, acc[q]);
            acc[q] = fmaf(p4.z, v2, acc[q]);
            acc[q] = fmaf(p4.w, v3, acc[q]);
        }
    }
    float* ob = out + (b * Qn + qbase) * Dv + tid;
    #pragma unroll
    for (int q = 0; q < TQ; ++q) ob[q * Dv] = acc[q] * rinv_s[q];
}

extern "C" void kernel_launch(void* const* d_in, const int* in_sizes, int n_in,
                              void* d_out, int out_size, void* d_ws, size_t ws_size,
                              hipStream_t stream) {
    const float* queries = (const float*)d_in[0];
    const float* keys    = (const float*)d_in[1];
    const float* values  = (const float*)d_in[2];
    const float* W_q     = (const float*)d_in[3];
    const float* W_k     = (const float*)d_in[4];
    const float* w_v     = (const float*)d_in[5];
    float* out = (float*)d_out;

    float* qp  = (float*)d_ws;                 // [B*Q, H]  1 MB
    float* kpt = qp + Bn * Qn * Hh;            // [B, H, K] 1 MB

    proj_kernel<<<Bn * Qn / 4, 256, 0, stream>>>(queries, W_q, qp, 0);
    proj_kernel<<<Bn * Kn / 4, 256, 0, stream>>>(keys, W_k, kpt, 1);
    attn_kernel<<<Bn * (Qn / TQ), 256, 0, stream>>>(qp, kpt, values, w_v, out);
}

// Round 2
// 175.485 us; speedup vs baseline: 1.7837x; 1.7837x over previous
//
#include <hip/hip_runtime.h>

#define Bn 4
#define Qn 1024
#define Kn 1024
#define Dd 256
#define Hh 64
#define Dv 256
#define TQ 8

__global__ __launch_bounds__(256) void proj_kernel(const float* __restrict__ Xq,
                                                   const float* __restrict__ Wq,
                                                   const float* __restrict__ Xk,
                                                   const float* __restrict__ Wk,
                                                   float* __restrict__ Eq,
                                                   float* __restrict__ Ekt) {
    int half = blockIdx.x >> 10;
    int bid = blockIdx.x & 1023;
    int row = bid * 4 + (threadIdx.x >> 6);
    int h = threadIdx.x & 63;
    const float* X = half ? Xk : Xq;
    const float* W = half ? Wk : Wq;
    const float4* x4 = (const float4*)(X + row * Dd);
    float acc = 0.f;
    #pragma unroll 8
    for (int d4 = 0; d4 < Dd / 4; ++d4) {
        float4 xv = x4[d4];
        int d = d4 * 4;
        acc = fmaf(xv.x, W[(d + 0) * Hh + h], acc);
        acc = fmaf(xv.y, W[(d + 1) * Hh + h], acc);
        acc = fmaf(xv.z, W[(d + 2) * Hh + h], acc);
        acc = fmaf(xv.w, W[(d + 3) * Hh + h], acc);
    }
    float e = __expf(2.f * acc);
    if (!half) {
        Eq[row * Hh + h] = e;
    } else {
        int b = row >> 10, k = row & 1023;
        Ekt[(b * Hh + h) * Kn + k] = e;
    }
}

// tanh(qp+kp) = 1 - 2/(Eq*Ek+1); weighted sum = W_sum - 2*s, W_sum cancels in
// softmax -> softmax over -2*s via exp(2*(min_s - s)).
__global__ __launch_bounds__(512) void attn_kernel(const float* __restrict__ Eq,
                                                   const float* __restrict__ Ekt,
                                                   const float* __restrict__ V,
                                                   const float* __restrict__ wv,
                                                   float* __restrict__ out) {
    __shared__ __align__(16) float sc[TQ * Kn];
    __shared__ __align__(16) float4 qp4[TQ * (Hh / 4)];
    __shared__ __align__(16) float wv_s[Hh];
    __shared__ float rinv_s[TQ];
    __shared__ __align__(16) float part[TQ * 256];

    int tid = threadIdx.x;
    int b = blockIdx.x >> 7;
    int qbase = (blockIdx.x & 127) * TQ;

    const float* qrow = Eq + (b * Qn + qbase) * Hh;
    ((float*)qp4)[tid] = qrow[tid];
    if (tid < Hh) wv_s[tid] = wv[tid];
    __syncthreads();

    const float* kb = Ekt + b * Hh * Kn;
    float s[TQ][2];
    #pragma unroll
    for (int q = 0; q < TQ; ++q) { s[q][0] = 0.f; s[q][1] = 0.f; }

    for (int h4 = 0; h4 < Hh / 4; ++h4) {
        float4 w4 = ((const float4*)wv_s)[h4];
        float4 qv[TQ];
        #pragma unroll
        for (int q = 0; q < TQ; ++q) qv[q] = qp4[q * (Hh / 4) + h4];
        const float* kh = kb + h4 * 4 * Kn;
        #pragma unroll
        for (int j = 0; j < 2; ++j) {
            int k = tid + j * 512;
            float e0 = kh[0 * Kn + k];
            float e1 = kh[1 * Kn + k];
            float e2 = kh[2 * Kn + k];
            float e3 = kh[3 * Kn + k];
            #pragma unroll
            for (int q = 0; q < TQ; ++q) {
                s[q][j] = fmaf(w4.x, __builtin_amdgcn_rcpf(fmaf(qv[q].x, e0, 1.f)), s[q][j]);
                s[q][j] = fmaf(w4.y, __builtin_amdgcn_rcpf(fmaf(qv[q].y, e1, 1.f)), s[q][j]);
                s[q][j] = fmaf(w4.z, __builtin_amdgcn_rcpf(fmaf(qv[q].z, e2, 1.f)), s[q][j]);
                s[q][j] = fmaf(w4.w, __builtin_amdgcn_rcpf(fmaf(qv[q].w, e3, 1.f)), s[q][j]);
            }
        }
    }
    #pragma unroll
    for (int j = 0; j < 2; ++j)
        #pragma unroll
        for (int q = 0; q < TQ; ++q) sc[q * Kn + tid + j * 512] = s[q][j];
    __syncthreads();

    int wave = tid >> 6, lane = tid & 63;
    {
        int q = wave;
        float m = 1e30f;
        for (int i = lane; i < Kn; i += 64) m = fminf(m, sc[q * Kn + i]);
        #pragma unroll
        for (int off = 32; off >= 1; off >>= 1) m = fminf(m, __shfl_xor(m, off, 64));
        float sum = 0.f;
        for (int i = lane; i < Kn; i += 64) {
            float e = __expf(2.f * (m - sc[q * Kn + i]));
            sc[q * Kn + i] = e;
            sum += e;
        }
        #pragma unroll
        for (int off = 32; off >= 1; off >>= 1) sum += __shfl_xor(sum, off, 64);
        if (lane == 0) rinv_s[q] = 1.f / sum;
    }
    __syncthreads();

    int col = tid & (Dv - 1), half = tid >> 8;
    float acc[TQ];
    #pragma unroll
    for (int q = 0; q < TQ; ++q) acc[q] = 0.f;
    const float* Vb = V + b * Kn * Dv + col;
    int k0 = half * (Kn / 2);
    for (int k = k0; k < k0 + Kn / 2; k += 4) {
        float v0 = Vb[(k + 0) * Dv];
        float v1 = Vb[(k + 1) * Dv];
        float v2 = Vb[(k + 2) * Dv];
        float v3 = Vb[(k + 3) * Dv];
        #pragma unroll
        for (int q = 0; q < TQ; ++q) {
            float4 p4 = *(const float4*)&sc[q * Kn + k];
            acc[q] = fmaf(p4.x, v0, acc[q]);
            acc[q] = fmaf(p4.y, v1, acc[q]);
            acc[q] = fmaf(p4.z, v2, acc[q]);
            acc[q] = fmaf(p4.w, v3, acc[q]);
        }
    }
    if (half) {
        #pragma unroll
        for (int q = 0; q < TQ; ++q) part[q * 256 + col] = acc[q];
    }
    __syncthreads();
    if (!half) {
        float* ob = out + (b * Qn + qbase) * Dv + col;
        #pragma unroll
        for (int q = 0; q < TQ; ++q)
            ob[q * Dv] = (acc[q] + part[q * 256 + col]) * rinv_s[q];
    }
}

extern "C" void kernel_launch(void* const* d_in, const int* in_sizes, int n_in,
                              void* d_out, int out_size, void* d_ws, size_t ws_size,
                              hipStream_t stream) {
    const float* queries = (const float*)d_in[0];
    const float* keys    = (const float*)d_in[1];
    const float* values  = (const float*)d_in[2];
    const float* W_q     = (const float*)d_in[3];
    const float* W_k     = (const float*)d_in[4];
    const float* w_v     = (const float*)d_in[5];
    float* out = (float*)d_out;

    float* Eq  = (float*)d_ws;                 // [B*Q, H]  1 MB
    float* Ekt = Eq + Bn * Qn * Hh;            // [B, H, K] 1 MB

    proj_kernel<<<2048, 256, 0, stream>>>(queries, W_q, keys, W_k, Eq, Ekt);
    attn_kernel<<<Bn * (Qn / TQ), 512, 0, stream>>>(Eq, Ekt, values, w_v, out);
}

// Round 3
// 165.276 us; speedup vs baseline: 1.8939x; 1.0618x over previous
//
#include <hip/hip_runtime.h>

#define Bn 4
#define Qn 1024
#define Kn 1024
#define Dd 256
#define Hh 64
#define Dv 256
#define TQ 8

// Projection v3: W staged in LDS once per block; each wave computes 8 rows
// so every W element fetched from LDS is reused 8x; 8 independent FMA chains.
// Blocks 0..127: q-side; 128..255: k-side (writes transposed [b,h,k]).
__global__ __launch_bounds__(256) void proj_kernel(const float* __restrict__ Xq,
                                                   const float* __restrict__ Wq,
                                                   const float* __restrict__ Xk,
                                                   const float* __restrict__ Wk,
                                                   float* __restrict__ Eq,
                                                   float* __restrict__ Ekt) {
    __shared__ __align__(16) float Wl[Dd * Hh];   // 64 KB
    int side = blockIdx.x >> 7;                    // 0: q, 1: k
    int bid = blockIdx.x & 127;
    const float* X = side ? Xk : Xq;
    const float* W = side ? Wk : Wq;
    int tid = threadIdx.x;

    for (int i = tid; i < Dd * Hh / 4; i += 256)
        ((float4*)Wl)[i] = ((const float4*)W)[i];
    __syncthreads();

    int wave = tid >> 6, h = tid & 63;
    int row0 = bid * 32 + wave * 8;                // 8 rows per wave
    float acc[8] = {0.f, 0.f, 0.f, 0.f, 0.f, 0.f, 0.f, 0.f};

    for (int d4 = 0; d4 < Dd / 4; ++d4) {
        float w0 = Wl[(d4 * 4 + 0) * Hh + h];      // banks h%32: 2-way, free
        float w1 = Wl[(d4 * 4 + 1) * Hh + h];
        float w2 = Wl[(d4 * 4 + 2) * Hh + h];
        float w3 = Wl[(d4 * 4 + 3) * Hh + h];
        #pragma unroll
        for (int r = 0; r < 8; ++r) {
            float4 xv = ((const float4*)(X + (row0 + r) * Dd))[d4];  // wave-uniform
            acc[r] = fmaf(xv.x, w0, acc[r]);
            acc[r] = fmaf(xv.y, w1, acc[r]);
            acc[r] = fmaf(xv.z, w2, acc[r]);
            acc[r] = fmaf(xv.w, w3, acc[r]);
        }
    }
    #pragma unroll
    for (int r = 0; r < 8; ++r) {
        int row = row0 + r;
        float e = __expf(2.f * acc[r]);
        if (!side) {
            Eq[row * Hh + h] = e;                  // coalesced
        } else {
            int b = row >> 10, k = row & 1023;
            Ekt[(b * Hh + h) * Kn + k] = e;        // scatter, ~1 us total
        }
    }
}

// tanh(qp+kp) = 1 - 2/(Eq*Ek+1); weighted sum = W_sum - 2*s, W_sum cancels in
// softmax -> softmax over -2*s via exp(2*(min_s - s)).
__global__ __launch_bounds__(512) void attn_kernel(const float* __restrict__ Eq,
                                                   const float* __restrict__ Ekt,
                                                   const float* __restrict__ V,
                                                   const float* __restrict__ wv,
                                                   float* __restrict__ out) {
    __shared__ __align__(16) float sc[TQ * Kn];
    __shared__ __align__(16) float4 qp4[TQ * (Hh / 4)];
    __shared__ __align__(16) float wv_s[Hh];
    __shared__ float rinv_s[TQ];
    __shared__ __align__(16) float part[TQ * 256];

    int tid = threadIdx.x;
    int b = blockIdx.x >> 7;
    int qbase = (blockIdx.x & 127) * TQ;

    const float* qrow = Eq + (b * Qn + qbase) * Hh;
    ((float*)qp4)[tid] = qrow[tid];
    if (tid < Hh) wv_s[tid] = wv[tid];
    __syncthreads();

    const float* kb = Ekt + b * Hh * Kn;
    float s[TQ][2];
    #pragma unroll
    for (int q = 0; q < TQ; ++q) { s[q][0] = 0.f; s[q][1] = 0.f; }

    for (int h4 = 0; h4 < Hh / 4; ++h4) {
        float4 w4 = ((const float4*)wv_s)[h4];
        float4 qv[TQ];
        #pragma unroll
        for (int q = 0; q < TQ; ++q) qv[q] = qp4[q * (Hh / 4) + h4];
        const float* kh = kb + h4 * 4 * Kn;
        #pragma unroll
        for (int j = 0; j < 2; ++j) {
            int k = tid + j * 512;
            float e0 = kh[0 * Kn + k];
            float e1 = kh[1 * Kn + k];
            float e2 = kh[2 * Kn + k];
            float e3 = kh[3 * Kn + k];
            #pragma unroll
            for (int q = 0; q < TQ; ++q) {
                s[q][j] = fmaf(w4.x, __builtin_amdgcn_rcpf(fmaf(qv[q].x, e0, 1.f)), s[q][j]);
                s[q][j] = fmaf(w4.y, __builtin_amdgcn_rcpf(fmaf(qv[q].y, e1, 1.f)), s[q][j]);
                s[q][j] = fmaf(w4.z, __builtin_amdgcn_rcpf(fmaf(qv[q].z, e2, 1.f)), s[q][j]);
                s[q][j] = fmaf(w4.w, __builtin_amdgcn_rcpf(fmaf(qv[q].w, e3, 1.f)), s[q][j]);
            }
        }
    }
    #pragma unroll
    for (int j = 0; j < 2; ++j)
        #pragma unroll
        for (int q = 0; q < TQ; ++q) sc[q * Kn + tid + j * 512] = s[q][j];
    __syncthreads();

    int wave = tid >> 6, lane = tid & 63;
    {
        int q = wave;
        float m = 1e30f;
        for (int i = lane; i < Kn; i += 64) m = fminf(m, sc[q * Kn + i]);
        #pragma unroll
        for (int off = 32; off >= 1; off >>= 1) m = fminf(m, __shfl_xor(m, off, 64));
        float sum = 0.f;
        for (int i = lane; i < Kn; i += 64) {
            float e = __expf(2.f * (m - sc[q * Kn + i]));
            sc[q * Kn + i] = e;
            sum += e;
        }
        #pragma unroll
        for (int off = 32; off >= 1; off >>= 1) sum += __shfl_xor(sum, off, 64);
        if (lane == 0) rinv_s[q] = 1.f / sum;
    }
    __syncthreads();

    int col = tid & (Dv - 1), half = tid >> 8;
    float acc[TQ];
    #pragma unroll
    for (int q = 0; q < TQ; ++q) acc[q] = 0.f;
    const float* Vb = V + b * Kn * Dv + col;
    int k0 = half * (Kn / 2);
    for (int k = k0; k < k0 + Kn / 2; k += 4) {
        float v0 = Vb[(k + 0) * Dv];
        float v1 = Vb[(k + 1) * Dv];
        float v2 = Vb[(k + 2) * Dv];
        float v3 = Vb[(k + 3) * Dv];
        #pragma unroll
        for (int q = 0; q < TQ; ++q) {
            float4 p4 = *(const float4*)&sc[q * Kn + k];
            acc[q] = fmaf(p4.x, v0, acc[q]);
            acc[q] = fmaf(p4.y, v1, acc[q]);
            acc[q] = fmaf(p4.z, v2, acc[q]);
            acc[q] = fmaf(p4.w, v3, acc[q]);
        }
    }
    if (half) {
        #pragma unroll
        for (int q = 0; q < TQ; ++q) part[q * 256 + col] = acc[q];
    }
    __syncthreads();
    if (!half) {
        float* ob = out + (b * Qn + qbase) * Dv + col;
        #pragma unroll
        for (int q = 0; q < TQ; ++q)
            ob[q * Dv] = (acc[q] + part[q * 256 + col]) * rinv_s[q];
    }
}

extern "C" void kernel_launch(void* const* d_in, const int* in_sizes, int n_in,
                              void* d_out, int out_size, void* d_ws, size_t ws_size,
                              hipStream_t stream) {
    const float* queries = (const float*)d_in[0];
    const float* keys    = (const float*)d_in[1];
    const float* values  = (const float*)d_in[2];
    const float* W_q     = (const float*)d_in[3];
    const float* W_k     = (const float*)d_in[4];
    const float* w_v     = (const float*)d_in[5];
    float* out = (float*)d_out;

    float* Eq  = (float*)d_ws;                 // [B*Q, H]  1 MB
    float* Ekt = Eq + Bn * Qn * Hh;            // [B, H, K] 1 MB

    proj_kernel<<<256, 256, 0, stream>>>(queries, W_q, keys, W_k, Eq, Ekt);
    attn_kernel<<<Bn * (Qn / TQ), 512, 0, stream>>>(Eq, Ekt, values, w_v, out);
}

// Round 4
// 141.423 us; speedup vs baseline: 2.2133x; 1.1687x over previous
//
#include <hip/hip_runtime.h>

#define Bn 4
#define Qn 1024
#define Kn 1024
#define Dd 256
#define Hh 64
#define Dv 256
#define TQ 8
#define SCP 1028   // sc row stride (floats): +4 pad -> conflict-free frag reads
#define PHP 1032   // P-bf16 row stride (shorts): 16B-aligned rows, bank spread

typedef __attribute__((ext_vector_type(8))) short short8;
typedef __attribute__((ext_vector_type(4))) float floatx4;

__device__ __forceinline__ short f32_to_bf16(float x) {
    unsigned u = __float_as_uint(x);
    unsigned r = u + 0x7fffu + ((u >> 16) & 1u);   // RNE
    return (short)(r >> 16);
}
__device__ __forceinline__ float bf16_to_f32(short h) {
    return __uint_as_float(((unsigned)(unsigned short)h) << 16);
}

// Projection v4: no LDS; W (64 KB) is L1/L2-resident. 4 rows per wave give 4x
// register reuse of each W element + 4 independent FMA chains. 512 blocks ->
// 8 waves/CU. Waves 0..1023: q-side; 1024..2047: k-side (transposed store).
__global__ __launch_bounds__(256) void proj_kernel(const float* __restrict__ Xq,
                                                   const float* __restrict__ Wq,
                                                   const float* __restrict__ Xk,
                                                   const float* __restrict__ Wk,
                                                   float* __restrict__ Eq,
                                                   float* __restrict__ Ekt) {
    int gw = blockIdx.x * 4 + (threadIdx.x >> 6);
    int h = threadIdx.x & 63;
    int side = gw >> 10;
    int row0 = (gw & 1023) * 4;
    const float* X = side ? Xk : Xq;
    const float* W = side ? Wk : Wq;
    float acc[4] = {0.f, 0.f, 0.f, 0.f};
    for (int d4 = 0; d4 < Dd / 4; ++d4) {
        float w0 = W[(d4 * 4 + 0) * Hh + h];
        float w1 = W[(d4 * 4 + 1) * Hh + h];
        float w2 = W[(d4 * 4 + 2) * Hh + h];
        float w3 = W[(d4 * 4 + 3) * Hh + h];
        #pragma unroll
        for (int r = 0; r < 4; ++r) {
            float4 xv = ((const float4*)(X + (row0 + r) * Dd))[d4];  // wave-uniform
            acc[r] = fmaf(xv.x, w0, acc[r]);
            acc[r] = fmaf(xv.y, w1, acc[r]);
            acc[r] = fmaf(xv.z, w2, acc[r]);
            acc[r] = fmaf(xv.w, w3, acc[r]);
        }
    }
    #pragma unroll
    for (int r = 0; r < 4; ++r) {
        int row = row0 + r;
        float e = __expf(2.f * acc[r]);
        if (!side) {
            Eq[row * Hh + h] = e;
        } else {
            int b = row >> 10, k = row & 1023;
            Ekt[(b * Hh + h) * Kn + k] = e;
        }
    }
}

// V prep: convert V to split bf16 (hi+lo) pre-swizzled into exact MFMA
// A-fragment order: VtF[((b*32+kt)*16+nt)*512 + lane*8 + j] holds
// V[kt*32 + (lane>>4)*8 + j][nt*16 + (lane&15)]. attn's A-loads become
// coalesced 16B/lane dwordx4.
__global__ __launch_bounds__(256) void vprep_kernel(const float* __restrict__ V,
                                                    short* __restrict__ Vhi,
                                                    short* __restrict__ Vlo) {
    __shared__ float tile[32 * 261];   // stride 261: kc*8*261 spreads banks
    int b = blockIdx.x >> 5;
    int kt = blockIdx.x & 31;
    int t = threadIdx.x;
    const float* Vg = V + (b * Kn + kt * 32) * Dv;
    for (int i = 0; i < 8; ++i) {
        int k = i * 4 + (t >> 6);
        int n4 = (t & 63) * 4;
        float4 v = *(const float4*)(Vg + k * Dv + n4);
        tile[k * 261 + n4 + 0] = v.x;
        tile[k * 261 + n4 + 1] = v.y;
        tile[k * 261 + n4 + 2] = v.z;
        tile[k * 261 + n4 + 3] = v.w;
    }
    __syncthreads();
    int wave = t >> 6, l = t & 63;
    int n_in = l & 15, kc = l >> 4;
    for (int p = 0; p < 4; ++p) {
        int nt = wave * 4 + p;
        int n = nt * 16 + n_in;
        short8 hi, lo;
        #pragma unroll
        for (int j = 0; j < 8; ++j) {
            float x = tile[(kc * 8 + j) * 261 + n];
            short hs = f32_to_bf16(x);
            float rest = x - bf16_to_f32(hs);
            hi[j] = hs;
            lo[j] = f32_to_bf16(rest);
        }
        size_t base = (((size_t)(b * 32 + kt) * 16 + nt) * 512) + (size_t)l * 8;
        *(short8*)(Vhi + base) = hi;
        *(short8*)(Vlo + base) = lo;
    }
}

// tanh(qp+kp) = 1 - 2/(Eq*Ek+1); weighted sum = W_sum - 2*s, W_sum cancels in
// softmax -> softmax over -2*s via exp(2*(min_s - s)). AV phase via
// mfma_f32_16x16x32_bf16 split-precision: out = Vhi*Phi + Vlo*Phi + Vhi*Plo.
__global__ __launch_bounds__(512) void attn_kernel(const float* __restrict__ Eq,
                                                   const float* __restrict__ Ekt,
                                                   const short* __restrict__ Vhi,
                                                   const short* __restrict__ Vlo,
                                                   const float* __restrict__ wv,
                                                   float* __restrict__ out) {
    __shared__ __align__(16) float sc[TQ * SCP];     // 32.9 KB
    __shared__ __align__(16) float4 qp4[TQ * (Hh / 4)];
    __shared__ __align__(16) float wv_s[Hh];
    __shared__ float rinv_s[TQ];
    __shared__ __align__(16) short Phi[TQ * PHP];    // 16.1 KB
    __shared__ __align__(16) short Plo[TQ * PHP];    // 16.1 KB

    int tid = threadIdx.x;
    int b = blockIdx.x >> 7;
    int qbase = (blockIdx.x & 127) * TQ;

    const float* qrow = Eq + (b * Qn + qbase) * Hh;
    ((float*)qp4)[tid] = qrow[tid];
    if (tid < Hh) wv_s[tid] = wv[tid];
    __syncthreads();

    // ---- score phase ----
    const float* kb = Ekt + b * Hh * Kn;
    float s[TQ][2];
    #pragma unroll
    for (int q = 0; q < TQ; ++q) { s[q][0] = 0.f; s[q][1] = 0.f; }

    for (int h4 = 0; h4 < Hh / 4; ++h4) {
        float4 w4 = ((const float4*)wv_s)[h4];
        float4 qv[TQ];
        #pragma unroll
        for (int q = 0; q < TQ; ++q) qv[q] = qp4[q * (Hh / 4) + h4];
        const float* kh = kb + h4 * 4 * Kn;
        #pragma unroll
        for (int j = 0; j < 2; ++j) {
            int k = tid + j * 512;
            float e0 = kh[0 * Kn + k];
            float e1 = kh[1 * Kn + k];
            float e2 = kh[2 * Kn + k];
            float e3 = kh[3 * Kn + k];
            #pragma unroll
            for (int q = 0; q < TQ; ++q) {
                s[q][j] = fmaf(w4.x, __builtin_amdgcn_rcpf(fmaf(qv[q].x, e0, 1.f)), s[q][j]);
                s[q][j] = fmaf(w4.y, __builtin_amdgcn_rcpf(fmaf(qv[q].y, e1, 1.f)), s[q][j]);
                s[q][j] = fmaf(w4.z, __builtin_amdgcn_rcpf(fmaf(qv[q].z, e2, 1.f)), s[q][j]);
                s[q][j] = fmaf(w4.w, __builtin_amdgcn_rcpf(fmaf(qv[q].w, e3, 1.f)), s[q][j]);
            }
        }
    }
    #pragma unroll
    for (int j = 0; j < 2; ++j)
        #pragma unroll
        for (int q = 0; q < TQ; ++q) sc[q * SCP + tid + j * 512] = s[q][j];
    __syncthreads();

    // ---- softmax over -2*s: wave w handles row q=w ----
    int wave = tid >> 6, lane = tid & 63;
    {
        int q = wave;
        float m = 1e30f;
        for (int i = lane; i < Kn; i += 64) m = fminf(m, sc[q * SCP + i]);
        #pragma unroll
        for (int off = 32; off >= 1; off >>= 1) m = fminf(m, __shfl_xor(m, off, 64));
        float sum = 0.f;
        for (int i = lane; i < Kn; i += 64) {
            float e = __expf(2.f * (m - sc[q * SCP + i]));
            sc[q * SCP + i] = e;
            sum += e;
        }
        #pragma unroll
        for (int off = 32; off >= 1; off >>= 1) sum += __shfl_xor(sum, off, 64);
        if (lane == 0) rinv_s[q] = 1.f / sum;
    }
    __syncthreads();

    // ---- convert P -> bf16 hi/lo (each element exactly once) ----
    for (int i = tid; i < TQ * Kn; i += 512) {
        int q = i >> 10, k = i & 1023;
        float x = sc[q * SCP + k];
        short hs = f32_to_bf16(x);
        Phi[q * PHP + k] = hs;
        Plo[q * PHP + k] = f32_to_bf16(x - bf16_to_f32(hs));
    }
    __syncthreads();

    // ---- AV via MFMA: wave owns ntiles {2w, 2w+1}; D[v][q] tiles ----
    int qf = lane & 15, kc = lane >> 4;
    int q8 = qf & 7;
    bool qok = qf < TQ;
    floatx4 acc0 = {0.f, 0.f, 0.f, 0.f};
    floatx4 acc1 = {0.f, 0.f, 0.f, 0.f};
    short8 z8 = (short8)(short)0;
    for (int kt = 0; kt < 32; ++kt) {
        int ks = kt * 32 + kc * 8;
        short8 bhi = *(const short8*)&Phi[q8 * PHP + ks];
        short8 blo = *(const short8*)&Plo[q8 * PHP + ks];
        if (!qok) { bhi = z8; blo = z8; }
        size_t base0 = (((size_t)(b * 32 + kt) * 16 + wave * 2 + 0) * 512) + (size_t)lane * 8;
        size_t base1 = (((size_t)(b * 32 + kt) * 16 + wave * 2 + 1) * 512) + (size_t)lane * 8;
        short8 a0h = *(const short8*)(Vhi + base0);
        short8 a0l = *(const short8*)(Vlo + base0);
        short8 a1h = *(const short8*)(Vhi + base1);
        short8 a1l = *(const short8*)(Vlo + base1);
        acc0 = __builtin_amdgcn_mfma_f32_16x16x32_bf16(a0h, bhi, acc0, 0, 0, 0);
        acc0 = __builtin_amdgcn_mfma_f32_16x16x32_bf16(a0l, bhi, acc0, 0, 0, 0);
        acc0 = __builtin_amdgcn_mfma_f32_16x16x32_bf16(a0h, blo, acc0, 0, 0, 0);
        acc1 = __builtin_amdgcn_mfma_f32_16x16x32_bf16(a1h, bhi, acc1, 0, 0, 0);
        acc1 = __builtin_amdgcn_mfma_f32_16x16x32_bf16(a1l, bhi, acc1, 0, 0, 0);
        acc1 = __builtin_amdgcn_mfma_f32_16x16x32_bf16(a1h, blo, acc1, 0, 0, 0);
    }
    if (qok) {
        float r = rinv_s[q8];
        float* ob = out + ((size_t)(b * Qn + qbase + qf)) * Dv + wave * 32 + kc * 4;
        float4 o0 = { acc0[0] * r, acc0[1] * r, acc0[2] * r, acc0[3] * r };
        float4 o1 = { acc1[0] * r, acc1[1] * r, acc1[2] * r, acc1[3] * r };
        *(float4*)(ob + 0)  = o0;
        *(float4*)(ob + 16) = o1;
    }
}

extern "C" void kernel_launch(void* const* d_in, const int* in_sizes, int n_in,
                              void* d_out, int out_size, void* d_ws, size_t ws_size,
                              hipStream_t stream) {
    const float* queries = (const float*)d_in[0];
    const float* keys    = (const float*)d_in[1];
    const float* values  = (const float*)d_in[2];
    const float* W_q     = (const float*)d_in[3];
    const float* W_k     = (const float*)d_in[4];
    const float* w_v     = (const float*)d_in[5];
    float* out = (float*)d_out;

    float* Eq  = (float*)d_ws;                 // [B*Q, H]      1 MB
    float* Ekt = Eq + Bn * Qn * Hh;            // [B, H, K]     1 MB
    short* Vhi = (short*)(Ekt + Bn * Kn * Hh); // frag-order    2 MB
    short* Vlo = Vhi + (size_t)Bn * Kn * Dv;   // frag-order    2 MB

    proj_kernel<<<512, 256, 0, stream>>>(queries, W_q, keys, W_k, Eq, Ekt);
    vprep_kernel<<<Bn * 32, 256, 0, stream>>>(values, Vhi, Vlo);
    attn_kernel<<<Bn * (Qn / TQ), 512, 0, stream>>>(Eq, Ekt, Vhi, Vlo, w_v, out);
}

// Round 5
// 141.249 us; speedup vs baseline: 2.2160x; 1.0012x over previous
//
#include <hip/hip_runtime.h>

#define Bn 4
#define Qn 1024
#define Kn 1024
#define Dd 256
#define Hh 64
#define Dv 256
#define TQ 16
#define SCP 1028   // sc row stride in floats (4112 B/row = 2056 shorts)

typedef __attribute__((ext_vector_type(8))) short short8;
typedef __attribute__((ext_vector_type(4))) float floatx4;

__device__ __forceinline__ short f32_to_bf16(float x) {
    unsigned u = __float_as_uint(x);
    unsigned r = u + 0x7fffu + ((u >> 16) & 1u);   // RNE
    return (short)(r >> 16);
}
__device__ __forceinline__ float bf16_to_f32(short h) {
    return __uint_as_float(((unsigned)(unsigned short)h) << 16);
}

// Fused prep: blocks 0..511 = projections (Eq + transposed Ekt, exp-folded);
// blocks 512..639 = V -> split-bf16 MFMA-A-fragment swizzle.
__global__ __launch_bounds__(256) void prep_kernel(const float* __restrict__ Xq,
                                                   const float* __restrict__ Wq,
                                                   const float* __restrict__ Xk,
                                                   const float* __restrict__ Wk,
                                                   const float* __restrict__ V,
                                                   float* __restrict__ Eq,
                                                   float* __restrict__ Ekt,
                                                   short* __restrict__ Vhi,
                                                   short* __restrict__ Vlo) {
    __shared__ float tile[32 * 261];
    int t = threadIdx.x;
    if (blockIdx.x < 512) {
        // ---- projection: 4 rows per wave, W L1/L2-resident ----
        int gw = blockIdx.x * 4 + (t >> 6);
        int h = t & 63;
        int side = gw >> 10;
        int row0 = (gw & 1023) * 4;
        const float* X = side ? Xk : Xq;
        const float* W = side ? Wk : Wq;
        float acc[4] = {0.f, 0.f, 0.f, 0.f};
        for (int d4 = 0; d4 < Dd / 4; ++d4) {
            float w0 = W[(d4 * 4 + 0) * Hh + h];
            float w1 = W[(d4 * 4 + 1) * Hh + h];
            float w2 = W[(d4 * 4 + 2) * Hh + h];
            float w3 = W[(d4 * 4 + 3) * Hh + h];
            #pragma unroll
            for (int r = 0; r < 4; ++r) {
                float4 xv = ((const float4*)(X + (row0 + r) * Dd))[d4];
                acc[r] = fmaf(xv.x, w0, acc[r]);
                acc[r] = fmaf(xv.y, w1, acc[r]);
                acc[r] = fmaf(xv.z, w2, acc[r]);
                acc[r] = fmaf(xv.w, w3, acc[r]);
            }
        }
        #pragma unroll
        for (int r = 0; r < 4; ++r) {
            int row = row0 + r;
            float e = __expf(2.f * acc[r]);
            if (!side) {
                Eq[row * Hh + h] = e;
            } else {
                int b = row >> 10, k = row & 1023;
                Ekt[(b * Hh + h) * Kn + k] = e;
            }
        }
    } else {
        // ---- V prep: swizzle into exact MFMA A-fragment order, hi+lo bf16 ----
        int blk = blockIdx.x - 512;
        int b = blk >> 5;
        int kt = blk & 31;
        const float* Vg = V + (b * Kn + kt * 32) * Dv;
        for (int i = 0; i < 8; ++i) {
            int k = i * 4 + (t >> 6);
            int n4 = (t & 63) * 4;
            float4 v = *(const float4*)(Vg + k * Dv + n4);
            tile[k * 261 + n4 + 0] = v.x;
            tile[k * 261 + n4 + 1] = v.y;
            tile[k * 261 + n4 + 2] = v.z;
            tile[k * 261 + n4 + 3] = v.w;
        }
        __syncthreads();
        int wave = t >> 6, l = t & 63;
        int n_in = l & 15, kc = l >> 4;
        for (int p = 0; p < 4; ++p) {
            int nt = wave * 4 + p;
            int n = nt * 16 + n_in;
            short8 hi, lo;
            #pragma unroll
            for (int j = 0; j < 8; ++j) {
                float x = tile[(kc * 8 + j) * 261 + n];
                short hs = f32_to_bf16(x);
                hi[j] = hs;
                lo[j] = f32_to_bf16(x - bf16_to_f32(hs));
            }
            size_t base = (((size_t)(b * 32 + kt) * 16 + nt) * 512) + (size_t)l * 8;
            *(short8*)(Vhi + base) = hi;
            *(short8*)(Vlo + base) = lo;
        }
    }
}

// score(q,k) = W_sum - 2*sum_h w_h/(Eq_h*Ek_h+1); W_sum cancels in softmax.
// Pairwise rcp: w1/a + w2/b = (w1*b + w2*a)*rcp(a*b)  (halves rcp count).
// P -> bf16 hi/lo converted IN PLACE over sc (row q's shorts fit in row q's
// float bytes), then AV via mfma_f32_16x16x32_bf16 split precision.
__global__ __launch_bounds__(512) void attn_kernel(const float* __restrict__ Eq,
                                                   const float* __restrict__ Ekt,
                                                   const short* __restrict__ Vhi,
                                                   const short* __restrict__ Vlo,
                                                   const float* __restrict__ wv,
                                                   float* __restrict__ out) {
    __shared__ __align__(16) float sc[TQ * SCP];       // 65.8 KB, reused as P hi/lo
    __shared__ __align__(16) float4 qp4[TQ * (Hh / 4)];// 4 KB
    __shared__ __align__(16) float wv_s[Hh];
    __shared__ float rinv_s[TQ];

    int tid = threadIdx.x;
    int b = blockIdx.x >> 6;                 // 64 q-tiles per batch
    int qbase = (blockIdx.x & 63) * TQ;

    const float* qrow = Eq + (b * Qn + qbase) * Hh;
    ((float*)qp4)[tid] = qrow[tid];
    ((float*)qp4)[tid + 512] = qrow[tid + 512];
    if (tid < Hh) wv_s[tid] = wv[tid];
    __syncthreads();

    // ---- score phase: thread owns k = tid + 512*j ----
    const float* kb = Ekt + b * Hh * Kn;
    float s[TQ][2];
    #pragma unroll
    for (int q = 0; q < TQ; ++q) { s[q][0] = 0.f; s[q][1] = 0.f; }

    for (int h4 = 0; h4 < Hh / 4; ++h4) {
        float4 w4 = ((const float4*)wv_s)[h4];
        const float* kh = kb + h4 * 4 * Kn;
        float e0[2], e1[2], e2[2], e3[2];
        #pragma unroll
        for (int j = 0; j < 2; ++j) {
            int k = tid + j * 512;
            e0[j] = kh[0 * Kn + k];
            e1[j] = kh[1 * Kn + k];
            e2[j] = kh[2 * Kn + k];
            e3[j] = kh[3 * Kn + k];
        }
        #pragma unroll 4
        for (int q = 0; q < TQ; ++q) {
            float4 qv = qp4[q * (Hh / 4) + h4];          // LDS b128 broadcast
            #pragma unroll
            for (int j = 0; j < 2; ++j) {
                float a  = fmaf(qv.x, e0[j], 1.f);
                float bb = fmaf(qv.y, e1[j], 1.f);
                float c  = fmaf(qv.z, e2[j], 1.f);
                float d  = fmaf(qv.w, e3[j], 1.f);
                float nab = fmaf(w4.x, bb, w4.y * a);
                float ncd = fmaf(w4.z, d, w4.w * c);
                s[q][j] = fmaf(nab, __builtin_amdgcn_rcpf(a * bb), s[q][j]);
                s[q][j] = fmaf(ncd, __builtin_amdgcn_rcpf(c * d), s[q][j]);
            }
        }
    }
    #pragma unroll
    for (int j = 0; j < 2; ++j)
        #pragma unroll
        for (int q = 0; q < TQ; ++q) sc[q * SCP + tid + j * 512] = s[q][j];
    __syncthreads();

    // ---- softmax over -2*s: wave w handles rows w, w+8 ----
    int wave = tid >> 6, lane = tid & 63;
    #pragma unroll
    for (int rr = 0; rr < 2; ++rr) {
        int q = wave + rr * 8;
        float m = 1e30f;
        for (int i = lane; i < Kn; i += 64) m = fminf(m, sc[q * SCP + i]);
        #pragma unroll
        for (int off = 32; off >= 1; off >>= 1) m = fminf(m, __shfl_xor(m, off, 64));
        float sum = 0.f;
        for (int i = lane; i < Kn; i += 64) {
            float e = __expf(2.f * (m - sc[q * SCP + i]));
            sc[q * SCP + i] = e;
            sum += e;
        }
        #pragma unroll
        for (int off = 32; off >= 1; off >>= 1) sum += __shfl_xor(sum, off, 64);
        if (lane == 0) rinv_s[q] = 1.f / sum;
    }
    __syncthreads();

    // ---- in-place convert P -> bf16 hi/lo over sc's own bytes ----
    // Row q (floats sc[q*SCP .. +1023]) becomes: hi shorts at short-idx
    // q*2056 + k (k<1024), lo shorts at q*2056 + 1024 + k.
    {
        int qa = wave, qb = wave + 8;
        float xa[16], xb[16];
        #pragma unroll
        for (int j = 0; j < 16; ++j) {
            xa[j] = sc[qa * SCP + lane + 64 * j];
            xb[j] = sc[qb * SCP + lane + 64 * j];
        }
        __syncthreads();
        short* sp = (short*)sc;
        #pragma unroll
        for (int j = 0; j < 16; ++j) {
            int k = lane + 64 * j;
            short ha = f32_to_bf16(xa[j]);
            short hb = f32_to_bf16(xb[j]);
            sp[qa * 2056 + k] = ha;
            sp[qa * 2056 + 1024 + k] = f32_to_bf16(xa[j] - bf16_to_f32(ha));
            sp[qb * 2056 + k] = hb;
            sp[qb * 2056 + 1024 + k] = f32_to_bf16(xb[j] - bf16_to_f32(hb));
        }
    }
    __syncthreads();

    // ---- AV via MFMA: wave owns ntiles {2w, 2w+1}; all 16 q-cols live ----
    int qf = lane & 15, kc = lane >> 4;
    floatx4 acc0 = {0.f, 0.f, 0.f, 0.f};
    floatx4 acc1 = {0.f, 0.f, 0.f, 0.f};
    const char* scb = (const char*)sc;
    for (int kt = 0; kt < 32; ++kt) {
        // B-frag: 16B at row-byte qf*4112 + kt*64 + kc*16 (start banks
        // 4*(qf+kc) mod 32 tile all banks -> conflict-free)
        short8 bhi = *(const short8*)(scb + qf * 4112 + kt * 64 + kc * 16);
        short8 blo = *(const short8*)(scb + qf * 4112 + 2048 + kt * 64 + kc * 16);
        size_t base0 = (((size_t)(b * 32 + kt) * 16 + wave * 2 + 0) * 512) + (size_t)lane * 8;
        size_t base1 = (((size_t)(b * 32 + kt) * 16 + wave * 2 + 1) * 512) + (size_t)lane * 8;
        short8 a0h = *(const short8*)(Vhi + base0);
        short8 a0l = *(const short8*)(Vlo + base0);
        short8 a1h = *(const short8*)(Vhi + base1);
        short8 a1l = *(const short8*)(Vlo + base1);
        acc0 = __builtin_amdgcn_mfma_f32_16x16x32_bf16(a0h, bhi, acc0, 0, 0, 0);
        acc0 = __builtin_amdgcn_mfma_f32_16x16x32_bf16(a0l, bhi, acc0, 0, 0, 0);
        acc0 = __builtin_amdgcn_mfma_f32_16x16x32_bf16(a0h, blo, acc0, 0, 0, 0);
        acc1 = __builtin_amdgcn_mfma_f32_16x16x32_bf16(a1h, bhi, acc1, 0, 0, 0);
        acc1 = __builtin_amdgcn_mfma_f32_16x16x32_bf16(a1l, bhi, acc1, 0, 0, 0);
        acc1 = __builtin_amdgcn_mfma_f32_16x16x32_bf16(a1h, blo, acc1, 0, 0, 0);
    }
    {
        float r = rinv_s[qf];
        float* ob = out + ((size_t)(b * Qn + qbase + qf)) * Dv + wave * 32 + kc * 4;
        float4 o0 = { acc0[0] * r, acc0[1] * r, acc0[2] * r, acc0[3] * r };
        float4 o1 = { acc1[0] * r, acc1[1] * r, acc1[2] * r, acc1[3] * r };
        *(float4*)(ob + 0)  = o0;
        *(float4*)(ob + 16) = o1;
    }
}

extern "C" void kernel_launch(void* const* d_in, const int* in_sizes, int n_in,
                              void* d_out, int out_size, void* d_ws, size_t ws_size,
                              hipStream_t stream) {
    const float* queries = (const float*)d_in[0];
    const float* keys    = (const float*)d_in[1];
    const float* values  = (const float*)d_in[2];
    const float* W_q     = (const float*)d_in[3];
    const float* W_k     = (const float*)d_in[4];
    const float* w_v     = (const float*)d_in[5];
    float* out = (float*)d_out;

    float* Eq  = (float*)d_ws;                 // [B*Q, H]      1 MB
    float* Ekt = Eq + Bn * Qn * Hh;            // [B, H, K]     1 MB
    short* Vhi = (short*)(Ekt + Bn * Kn * Hh); // frag-order    2 MB
    short* Vlo = Vhi + (size_t)Bn * Kn * Dv;   // frag-order    2 MB

    prep_kernel<<<640, 256, 0, stream>>>(queries, W_q, keys, W_k, values,
                                         Eq, Ekt, Vhi, Vlo);
    attn_kernel<<<Bn * (Qn / TQ), 512, 0, stream>>>(Eq, Ekt, Vhi, Vlo, w_v, out);
}